// Round 8
// baseline (65.755 us; speedup 1.0000x reference)
//
#include <hip/hip_runtime.h>
#include <hip/hip_bf16.h>

typedef unsigned short u16;
typedef __attribute__((ext_vector_type(8))) __bf16 bf16x8;
typedef __attribute__((ext_vector_type(4))) float f32x4;

#define B_ 4
#define T_ 2048
#define C_ 1024
#define H_ 64
#define NSEG 8

__device__ __forceinline__ u16 f2bf(float f) {
    union { __hip_bfloat16 h; u16 u; } cv;
    cv.h = __float2bfloat16(f);
    return cv.u;
}

__device__ __forceinline__ float bf2f(unsigned v) {
    union { unsigned u; float f; } c; c.u = v << 16; return c.f;
}

__device__ __forceinline__ bf16x8 cvt8r(float4 f0, float4 f1) {
    union { u16 h[8]; bf16x8 v; } ua;
    ua.h[0] = f2bf(f0.x); ua.h[1] = f2bf(f0.y);
    ua.h[2] = f2bf(f0.z); ua.h[3] = f2bf(f0.w);
    ua.h[4] = f2bf(f1.x); ua.h[5] = f2bf(f1.y);
    ua.h[6] = f2bf(f1.z); ua.h[7] = f2bf(f1.w);
    return ua.v;
}

// ---------------- Kernel 0: W fp32 -> bf16 (once) ----------------
__global__ __launch_bounds__(256) void wcvt(
    const float* __restrict__ wq, const float* __restrict__ wk,
    const float* __restrict__ wv, u16* __restrict__ wcat)
{
    int e = (blockIdx.x * 256 + threadIdx.x) * 4;
    int row = e >> 10, col = e & 1023;
    const float* src = (row < 64) ? (wq + (size_t)row * C_)
                     : (row < 128) ? (wk + (size_t)(row - 64) * C_)
                                   : (wv + (size_t)(row - 128) * C_);
    float4 f = *(const float4*)(src + col);
    u16 o[4] = { f2bf(f.x), f2bf(f.y), f2bf(f.z), f2bf(f.w) };
    *(uint2*)(wcat + e) = *(uint2*)o;
}

// ---------------- Kernel 1: QKV projection ----------------
// Block = 16-row M-tile, 8 waves = K-split x8 (wave w owns K [w*128,(w+1)*128)).
// 512 blocks, 50 KB LDS -> 2 blocks/CU, 16 waves/CU.
__global__ __launch_bounds__(512, 4) void qkv(
    const float* __restrict__ x, const u16* __restrict__ wcat,
    u16* __restrict__ q, u16* __restrict__ k, u16* __restrict__ vT)
{
    __shared__ float red[4][16][196];   // 50.2 KB; worst 2-way bank alias (free)

    const int tid  = threadIdx.x;
    const int lane = tid & 63;
    const int w    = tid >> 6;          // 0..7 = K-slice
    const int m0   = blockIdx.x * 16;

    const int lr = lane & 15;
    const int g  = lane >> 4;

    const size_t kbase = (size_t)w * 128 + g * 8;
    const float* xr = x + (size_t)(m0 + lr) * C_ + kbase;
    const u16*   wb = wcat + (size_t)lr * C_ + kbase;

    f32x4 acc[12] = {};

    #pragma unroll
    for (int ks = 0; ks < 4; ++ks) {
        float4 f0 = *(const float4*)(xr + ks * 32);
        float4 f1 = *(const float4*)(xr + ks * 32 + 4);
        bf16x8 a = cvt8r(f0, f1);
        #pragma unroll
        for (int j = 0; j < 12; ++j) {
            bf16x8 b = *(const bf16x8*)(wb + (size_t)j * 16 * C_ + ks * 32);
            acc[j] = __builtin_amdgcn_mfma_f32_16x16x32_bf16(a, b, acc[j], 0, 0, 0);
        }
    }

    // tree reduction 8 -> 4 -> 2 -> 1
    if (w >= 4)
        #pragma unroll
        for (int j = 0; j < 12; ++j)
            #pragma unroll
            for (int i = 0; i < 4; ++i)
                red[w - 4][g * 4 + i][j * 16 + lr] = acc[j][i];
    __syncthreads();
    if (w < 4)
        #pragma unroll
        for (int j = 0; j < 12; ++j)
            #pragma unroll
            for (int i = 0; i < 4; ++i)
                acc[j][i] += red[w][g * 4 + i][j * 16 + lr];
    __syncthreads();
    if (w == 2 || w == 3)
        #pragma unroll
        for (int j = 0; j < 12; ++j)
            #pragma unroll
            for (int i = 0; i < 4; ++i)
                red[w - 2][g * 4 + i][j * 16 + lr] = acc[j][i];
    __syncthreads();
    if (w < 2)
        #pragma unroll
        for (int j = 0; j < 12; ++j)
            #pragma unroll
            for (int i = 0; i < 4; ++i)
                acc[j][i] += red[w][g * 4 + i][j * 16 + lr];
    __syncthreads();
    if (w == 1)
        #pragma unroll
        for (int j = 0; j < 12; ++j)
            #pragma unroll
            for (int i = 0; i < 4; ++i)
                red[0][g * 4 + i][j * 16 + lr] = acc[j][i];
    __syncthreads();
    if (w != 0) return;

    // wave 0: final add + epilogue (C/D layout col=lane&15, row=(lane>>4)*4+i)
    #pragma unroll
    for (int j = 0; j < 12; ++j) {
        int n = j * 16 + lr;
        #pragma unroll
        for (int i = 0; i < 4; ++i) {
            float sum = acc[j][i] + red[0][g * 4 + i][j * 16 + lr];
            int m = m0 + g * 4 + i;
            u16 val = f2bf(sum);
            if (n < 64) {
                q[(size_t)m * H_ + n] = val;
            } else if (n < 128) {
                k[(size_t)m * H_ + (n - 64)] = val;
            } else {
                int b = m >> 11, t = m & 2047;
                vT[((size_t)b * H_ + (n - 128)) * T_ + t] = val;
            }
        }
    }
}

// ---------------- Kernel 2: causal flash attention, KV-split x8 ----------
// 1-wave blocks: no barriers needed (intra-wave LDS ordering via lgkmcnt).
__global__ __launch_bounds__(64) void attn_part(
    const u16* __restrict__ q, const u16* __restrict__ k,
    const u16* __restrict__ vT, u16* __restrict__ opart,
    float* __restrict__ ml)
{
    __shared__ u16 ps[16 * 72];

    const int lane = threadIdx.x;
    const int bid  = blockIdx.x;
    const int seg  = bid & (NSEG - 1);
    const int tix  = bid >> 3;
    const int b    = tix & 3;
    const int qt   = 127 - (tix >> 2);
    const int q0   = qt * 16;
    const size_t bT = (size_t)b * T_;

    const int lr = lane & 15;
    const int g  = lane >> 4;
    const int lk = g * 8;

    const int nch = (qt >> 2) + 1;
    const int L   = (nch + NSEG - 1) >> 3;
    const int c0  = seg * L;
    const int c1  = min(nch, c0 + L);

    if (c0 >= c1) {
        if (lr == 0)
            #pragma unroll
            for (int i = 0; i < 4; ++i) {
                ml[(size_t)bid * 32 + (g * 4 + i) * 2]     = -1e30f;
                ml[(size_t)bid * 32 + (g * 4 + i) * 2 + 1] = 0.f;
            }
        return;
    }

    bf16x8 aq[2];
    #pragma unroll
    for (int ks = 0; ks < 2; ++ks)
        aq[ks] = *(const bf16x8*)(q + (bT + q0 + lr) * H_ + ks * 32 + lk);

    f32x4 oacc[4] = {};
    float mrow[4], lrow[4];
    #pragma unroll
    for (int i = 0; i < 4; ++i) { mrow[i] = -1e30f; lrow[i] = 0.f; }

    for (int jc = c0; jc < c1; ++jc) {
        const int kv0 = jc << 6;

        // K fragments + QK^T
        bf16x8 bk[8];
        #pragma unroll
        for (int jf = 0; jf < 4; ++jf)
            #pragma unroll
            for (int ks = 0; ks < 2; ++ks)
                bk[jf * 2 + ks] = *(const bf16x8*)(k + (bT + kv0 + jf * 16 + lr) * H_ + ks * 32 + lk);

        f32x4 sacc[4] = {};
        #pragma unroll
        for (int jf = 0; jf < 4; ++jf)
            #pragma unroll
            for (int ks = 0; ks < 2; ++ks)
                sacc[jf] = __builtin_amdgcn_mfma_f32_16x16x32_bf16(aq[ks], bk[jf * 2 + ks], sacc[jf], 0, 0, 0);

        // V fragments issued BEFORE softmax: latency hides under exp/shuffles
        bf16x8 bv[8];
        #pragma unroll
        for (int jf = 0; jf < 4; ++jf)
            #pragma unroll
            for (int ks = 0; ks < 2; ++ks)
                bv[jf * 2 + ks] = *(const bf16x8*)(vT + ((size_t)b * H_ + jf * 16 + lr) * T_ + kv0 + ks * 32 + lk);

        // scale + causal mask (in place)
        const bool full = (kv0 + 63 <= q0);
        #pragma unroll
        for (int jf = 0; jf < 4; ++jf) {
            int col = kv0 + jf * 16 + lr;
            #pragma unroll
            for (int i = 0; i < 4; ++i) {
                int row = q0 + g * 4 + i;
                float val = sacc[jf][i] * 0.03125f;
                sacc[jf][i] = (full || col <= row) ? val : -1e30f;
            }
        }

        // online softmax
        float pnew[4][4];
        #pragma unroll
        for (int i = 0; i < 4; ++i) {
            float mx = fmaxf(fmaxf(sacc[0][i], sacc[1][i]), fmaxf(sacc[2][i], sacc[3][i]));
            mx = fmaxf(mx, __shfl_xor(mx, 1));
            mx = fmaxf(mx, __shfl_xor(mx, 2));
            mx = fmaxf(mx, __shfl_xor(mx, 4));
            mx = fmaxf(mx, __shfl_xor(mx, 8));
            float mnew = fmaxf(mrow[i], mx);
            float corr = __expf(mrow[i] - mnew);
            float rs = 0.f;
            #pragma unroll
            for (int jf = 0; jf < 4; ++jf) {
                float p = __expf(sacc[jf][i] - mnew);
                pnew[jf][i] = p;
                rs += p;
            }
            rs += __shfl_xor(rs, 1);
            rs += __shfl_xor(rs, 2);
            rs += __shfl_xor(rs, 4);
            rs += __shfl_xor(rs, 8);
            lrow[i] = lrow[i] * corr + rs;
            mrow[i] = mnew;
            #pragma unroll
            for (int jf = 0; jf < 4; ++jf) oacc[jf][i] *= corr;
        }

        // P -> LDS (C/D -> A layout) -- single wave, no barrier needed
        #pragma unroll
        for (int jf = 0; jf < 4; ++jf)
            #pragma unroll
            for (int i = 0; i < 4; ++i)
                ps[(g * 4 + i) * 72 + jf * 16 + lr] = f2bf(pnew[jf][i]);

        #pragma unroll
        for (int ks2 = 0; ks2 < 2; ++ks2) {
            bf16x8 ap = *(const bf16x8*)(ps + lr * 72 + ks2 * 32 + lk);
            #pragma unroll
            for (int jf = 0; jf < 4; ++jf)
                oacc[jf] = __builtin_amdgcn_mfma_f32_16x16x32_bf16(ap, bv[jf * 2 + ks2], oacc[jf], 0, 0, 0);
        }
    }

    #pragma unroll
    for (int jf = 0; jf < 4; ++jf)
        #pragma unroll
        for (int i = 0; i < 4; ++i)
            opart[(size_t)bid * 1024 + (g * 4 + i) * 64 + jf * 16 + lr] = f2bf(oacc[jf][i]);
    if (lr == 0)
        #pragma unroll
        for (int i = 0; i < 4; ++i) {
            ml[(size_t)bid * 32 + (g * 4 + i) * 2]     = mrow[i];
            ml[(size_t)bid * 32 + (g * 4 + i) * 2 + 1] = lrow[i];
        }
}

// ---------------- Kernel 3: merge segments (bf16 partials) ----------------
__global__ __launch_bounds__(256) void attn_reduce(
    const u16* __restrict__ opart, const float* __restrict__ ml,
    float* __restrict__ out)
{
    const int t   = blockIdx.x;
    const int row = threadIdx.x >> 4;
    const int p   = threadIdx.x & 15;
    const int b   = t & 3;
    const int qt  = 127 - (t >> 2);

    float m[NSEG], l[NSEG];
    #pragma unroll
    for (int s = 0; s < NSEG; ++s) {
        m[s] = ml[(size_t)(t * NSEG + s) * 32 + row * 2];
        l[s] = ml[(size_t)(t * NSEG + s) * 32 + row * 2 + 1];
    }
    float M = m[0];
    #pragma unroll
    for (int s = 1; s < NSEG; ++s) M = fmaxf(M, m[s]);

    float a0 = 0.f, a1 = 0.f, a2 = 0.f, a3 = 0.f, Lsum = 0.f;
    #pragma unroll
    for (int s = 0; s < NSEG; ++s) {
        float wgt = __expf(m[s] - M);
        Lsum += l[s] * wgt;
        uint2 o = *(const uint2*)(opart + (size_t)(t * NSEG + s) * 1024 + row * 64 + p * 4);
        a0 += wgt * bf2f(o.x & 0xffffu);
        a1 += wgt * bf2f(o.x >> 16);
        a2 += wgt * bf2f(o.y & 0xffffu);
        a3 += wgt * bf2f(o.y >> 16);
    }
    float inv = 1.f / Lsum;
    float4 r; r.x = a0 * inv; r.y = a1 * inv; r.z = a2 * inv; r.w = a3 * inv;
    *(float4*)(out + ((size_t)b * T_ + qt * 16 + row) * H_ + p * 4) = r;
}

extern "C" void kernel_launch(void* const* d_in, const int* in_sizes, int n_in,
                              void* d_out, int out_size, void* d_ws, size_t ws_size,
                              hipStream_t stream) {
    const float* x  = (const float*)d_in[0];
    const float* wq = (const float*)d_in[1];
    const float* wk = (const float*)d_in[2];
    const float* wv = (const float*)d_in[3];

    u16* qws  = (u16*)d_ws;                          // 1 MB
    u16* kws  = qws + (size_t)B_ * T_ * H_;          // 1 MB
    u16* vTws = kws + (size_t)B_ * T_ * H_;          // 1 MB
    u16* wcat = vTws + (size_t)B_ * T_ * H_;         // 384 KB
    u16* opart = wcat + (size_t)192 * C_;            // 4096*1024 u16 = 8.4 MB
    float* mlbuf = (float*)(opart + (size_t)4096 * 1024);  // 512 KB

    wcvt<<<192, 256, 0, stream>>>(wq, wk, wv, wcat);
    qkv<<<512, 512, 0, stream>>>(x, wcat, qws, kws, vTws);
    attn_part<<<4096, 64, 0, stream>>>(qws, kws, vTws, opart, mlbuf);
    attn_reduce<<<512, 256, 0, stream>>>(opart, mlbuf, (float*)d_out);
}

// Round 9
// 57.465 us; speedup vs baseline: 1.1443x; 1.1443x over previous
//
#include <hip/hip_runtime.h>
#include <hip/hip_bf16.h>

typedef unsigned short u16;
typedef __attribute__((ext_vector_type(8))) __bf16 bf16x8;
typedef __attribute__((ext_vector_type(4))) float f32x4;

#define B_ 4
#define T_ 2048
#define C_ 1024
#define H_ 64
#define NSEG 8

__device__ __forceinline__ u16 f2bf(float f) {
    union { __hip_bfloat16 h; u16 u; } cv;
    cv.h = __float2bfloat16(f);
    return cv.u;
}

__device__ __forceinline__ float bf2f(unsigned v) {
    union { unsigned u; float f; } c; c.u = v << 16; return c.f;
}

__device__ __forceinline__ bf16x8 cvt8r(float4 f0, float4 f1) {
    union { u16 h[8]; bf16x8 v; } ua;
    ua.h[0] = f2bf(f0.x); ua.h[1] = f2bf(f0.y);
    ua.h[2] = f2bf(f0.z); ua.h[3] = f2bf(f0.w);
    ua.h[4] = f2bf(f1.x); ua.h[5] = f2bf(f1.y);
    ua.h[6] = f2bf(f1.z); ua.h[7] = f2bf(f1.w);
    return ua.v;
}

// ---------------- Kernel 0: W fp32 -> bf16 (once) ----------------
__global__ __launch_bounds__(256) void wcvt(
    const float* __restrict__ wq, const float* __restrict__ wk,
    const float* __restrict__ wv, u16* __restrict__ wcat)
{
    int e = (blockIdx.x * 256 + threadIdx.x) * 4;
    int row = e >> 10, col = e & 1023;
    const float* src = (row < 64) ? (wq + (size_t)row * C_)
                     : (row < 128) ? (wk + (size_t)(row - 64) * C_)
                                   : (wv + (size_t)(row - 128) * C_);
    float4 f = *(const float4*)(src + col);
    u16 o[4] = { f2bf(f.x), f2bf(f.y), f2bf(f.z), f2bf(f.w) };
    *(uint2*)(wcat + e) = *(uint2*)o;
}

// ---------------- Kernel 1: QKV projection (R7 known-good) ----------------
// Block = 32-row M-tile, 8 waves, K-split x8 (wave w owns K [w*128,(w+1)*128)).
__global__ __launch_bounds__(512, 2) void qkv(
    const float* __restrict__ x, const u16* __restrict__ wcat,
    u16* __restrict__ q, u16* __restrict__ k, u16* __restrict__ vT)
{
    __shared__ float red[4][32][193];   // 96.5 KB; stride 193 -> conflict-free

    const int tid  = threadIdx.x;
    const int lane = tid & 63;
    const int w    = tid >> 6;          // 0..7 = K-slice
    const int m0   = blockIdx.x * 32;

    const int lr = lane & 15;
    const int g  = lane >> 4;

    const size_t kbase = (size_t)w * 128 + g * 8;
    const float* xr0 = x + (size_t)(m0 + lr) * C_ + kbase;
    const float* xr1 = x + (size_t)(m0 + 16 + lr) * C_ + kbase;
    const u16*   wb  = wcat + (size_t)lr * C_ + kbase;

    f32x4 acc[2][12] = {};

    #pragma unroll
    for (int ks = 0; ks < 4; ++ks) {
        float4 f00 = *(const float4*)(xr0 + ks * 32);
        float4 f01 = *(const float4*)(xr0 + ks * 32 + 4);
        float4 f10 = *(const float4*)(xr1 + ks * 32);
        float4 f11 = *(const float4*)(xr1 + ks * 32 + 4);
        bf16x8 a0 = cvt8r(f00, f01);
        bf16x8 a1 = cvt8r(f10, f11);
        #pragma unroll
        for (int j = 0; j < 12; ++j) {
            bf16x8 b = *(const bf16x8*)(wb + (size_t)j * 16 * C_ + ks * 32);
            acc[0][j] = __builtin_amdgcn_mfma_f32_16x16x32_bf16(a0, b, acc[0][j], 0, 0, 0);
            acc[1][j] = __builtin_amdgcn_mfma_f32_16x16x32_bf16(a1, b, acc[1][j], 0, 0, 0);
        }
    }

    // tree reduction: 8 -> 4 -> 2 -> 1
    if (w >= 4)
        #pragma unroll
        for (int ms = 0; ms < 2; ++ms)
            #pragma unroll
            for (int j = 0; j < 12; ++j)
                #pragma unroll
                for (int i = 0; i < 4; ++i)
                    red[w - 4][ms * 16 + g * 4 + i][j * 16 + lr] = acc[ms][j][i];
    __syncthreads();
    if (w < 4)
        #pragma unroll
        for (int ms = 0; ms < 2; ++ms)
            #pragma unroll
            for (int j = 0; j < 12; ++j)
                #pragma unroll
                for (int i = 0; i < 4; ++i)
                    acc[ms][j][i] += red[w][ms * 16 + g * 4 + i][j * 16 + lr];
    __syncthreads();
    if (w == 2 || w == 3)
        #pragma unroll
        for (int ms = 0; ms < 2; ++ms)
            #pragma unroll
            for (int j = 0; j < 12; ++j)
                #pragma unroll
                for (int i = 0; i < 4; ++i)
                    red[w - 2][ms * 16 + g * 4 + i][j * 16 + lr] = acc[ms][j][i];
    __syncthreads();
    if (w < 2)
        #pragma unroll
        for (int ms = 0; ms < 2; ++ms)
            #pragma unroll
            for (int j = 0; j < 12; ++j)
                #pragma unroll
                for (int i = 0; i < 4; ++i)
                    acc[ms][j][i] += red[w][ms * 16 + g * 4 + i][j * 16 + lr];
    __syncthreads();
    if (w == 1)
        #pragma unroll
        for (int ms = 0; ms < 2; ++ms)
            #pragma unroll
            for (int j = 0; j < 12; ++j)
                #pragma unroll
                for (int i = 0; i < 4; ++i)
                    red[0][ms * 16 + g * 4 + i][j * 16 + lr] = acc[ms][j][i];
    __syncthreads();
    if (w != 0) return;

    // epilogue (wave 0): C/D layout col=lane&15, row=(lane>>4)*4+i
    #pragma unroll
    for (int j = 0; j < 12; ++j) {
        int n = j * 16 + lr;
        #pragma unroll
        for (int ms = 0; ms < 2; ++ms)
            #pragma unroll
            for (int i = 0; i < 4; ++i) {
                float sum = acc[ms][j][i] + red[0][ms * 16 + g * 4 + i][j * 16 + lr];
                int m = m0 + ms * 16 + g * 4 + i;
                u16 val = f2bf(sum);
                if (n < 64) {
                    q[(size_t)m * H_ + n] = val;
                } else if (n < 128) {
                    k[(size_t)m * H_ + (n - 64)] = val;
                } else {
                    int b = m >> 11, t = m & 2047;
                    vT[((size_t)b * H_ + (n - 128)) * T_ + t] = val;
                }
            }
    }
}

// ---------------- Kernel 2: causal flash attention, KV-split x8 ----------
// 1-wave blocks: no barriers (intra-wave LDS ordering via lgkmcnt); V hoisted.
__global__ __launch_bounds__(64) void attn_part(
    const u16* __restrict__ q, const u16* __restrict__ k,
    const u16* __restrict__ vT, u16* __restrict__ opart,
    float* __restrict__ ml)
{
    __shared__ u16 ps[16 * 72];

    const int lane = threadIdx.x;
    const int bid  = blockIdx.x;
    const int seg  = bid & (NSEG - 1);
    const int tix  = bid >> 3;
    const int b    = tix & 3;
    const int qt   = 127 - (tix >> 2);
    const int q0   = qt * 16;
    const size_t bT = (size_t)b * T_;

    const int lr = lane & 15;
    const int g  = lane >> 4;
    const int lk = g * 8;

    const int nch = (qt >> 2) + 1;
    const int L   = (nch + NSEG - 1) >> 3;
    const int c0  = seg * L;
    const int c1  = min(nch, c0 + L);

    if (c0 >= c1) {
        if (lr == 0)
            #pragma unroll
            for (int i = 0; i < 4; ++i) {
                ml[(size_t)bid * 32 + (g * 4 + i) * 2]     = -1e30f;
                ml[(size_t)bid * 32 + (g * 4 + i) * 2 + 1] = 0.f;
            }
        return;
    }

    bf16x8 aq[2];
    #pragma unroll
    for (int ks = 0; ks < 2; ++ks)
        aq[ks] = *(const bf16x8*)(q + (bT + q0 + lr) * H_ + ks * 32 + lk);

    f32x4 oacc[4] = {};
    float mrow[4], lrow[4];
    #pragma unroll
    for (int i = 0; i < 4; ++i) { mrow[i] = -1e30f; lrow[i] = 0.f; }

    for (int jc = c0; jc < c1; ++jc) {
        const int kv0 = jc << 6;

        bf16x8 bk[8];
        #pragma unroll
        for (int jf = 0; jf < 4; ++jf)
            #pragma unroll
            for (int ks = 0; ks < 2; ++ks)
                bk[jf * 2 + ks] = *(const bf16x8*)(k + (bT + kv0 + jf * 16 + lr) * H_ + ks * 32 + lk);

        f32x4 sacc[4] = {};
        #pragma unroll
        for (int jf = 0; jf < 4; ++jf)
            #pragma unroll
            for (int ks = 0; ks < 2; ++ks)
                sacc[jf] = __builtin_amdgcn_mfma_f32_16x16x32_bf16(aq[ks], bk[jf * 2 + ks], sacc[jf], 0, 0, 0);

        // V fragments issued BEFORE softmax: latency hides under exp/shuffles
        bf16x8 bv[8];
        #pragma unroll
        for (int jf = 0; jf < 4; ++jf)
            #pragma unroll
            for (int ks = 0; ks < 2; ++ks)
                bv[jf * 2 + ks] = *(const bf16x8*)(vT + ((size_t)b * H_ + jf * 16 + lr) * T_ + kv0 + ks * 32 + lk);

        const bool full = (kv0 + 63 <= q0);
        #pragma unroll
        for (int jf = 0; jf < 4; ++jf) {
            int col = kv0 + jf * 16 + lr;
            #pragma unroll
            for (int i = 0; i < 4; ++i) {
                int row = q0 + g * 4 + i;
                float val = sacc[jf][i] * 0.03125f;
                sacc[jf][i] = (full || col <= row) ? val : -1e30f;
            }
        }

        float pnew[4][4];
        #pragma unroll
        for (int i = 0; i < 4; ++i) {
            float mx = fmaxf(fmaxf(sacc[0][i], sacc[1][i]), fmaxf(sacc[2][i], sacc[3][i]));
            mx = fmaxf(mx, __shfl_xor(mx, 1));
            mx = fmaxf(mx, __shfl_xor(mx, 2));
            mx = fmaxf(mx, __shfl_xor(mx, 4));
            mx = fmaxf(mx, __shfl_xor(mx, 8));
            float mnew = fmaxf(mrow[i], mx);
            float corr = __expf(mrow[i] - mnew);
            float rs = 0.f;
            #pragma unroll
            for (int jf = 0; jf < 4; ++jf) {
                float p = __expf(sacc[jf][i] - mnew);
                pnew[jf][i] = p;
                rs += p;
            }
            rs += __shfl_xor(rs, 1);
            rs += __shfl_xor(rs, 2);
            rs += __shfl_xor(rs, 4);
            rs += __shfl_xor(rs, 8);
            lrow[i] = lrow[i] * corr + rs;
            mrow[i] = mnew;
            #pragma unroll
            for (int jf = 0; jf < 4; ++jf) oacc[jf][i] *= corr;
        }

        // P -> LDS (C/D -> A layout) -- single wave, no barrier needed
        #pragma unroll
        for (int jf = 0; jf < 4; ++jf)
            #pragma unroll
            for (int i = 0; i < 4; ++i)
                ps[(g * 4 + i) * 72 + jf * 16 + lr] = f2bf(pnew[jf][i]);

        #pragma unroll
        for (int ks2 = 0; ks2 < 2; ++ks2) {
            bf16x8 ap = *(const bf16x8*)(ps + lr * 72 + ks2 * 32 + lk);
            #pragma unroll
            for (int jf = 0; jf < 4; ++jf)
                oacc[jf] = __builtin_amdgcn_mfma_f32_16x16x32_bf16(ap, bv[jf * 2 + ks2], oacc[jf], 0, 0, 0);
        }
    }

    #pragma unroll
    for (int jf = 0; jf < 4; ++jf)
        #pragma unroll
        for (int i = 0; i < 4; ++i)
            opart[(size_t)bid * 1024 + (g * 4 + i) * 64 + jf * 16 + lr] = f2bf(oacc[jf][i]);
    if (lr == 0)
        #pragma unroll
        for (int i = 0; i < 4; ++i) {
            ml[(size_t)bid * 32 + (g * 4 + i) * 2]     = mrow[i];
            ml[(size_t)bid * 32 + (g * 4 + i) * 2 + 1] = lrow[i];
        }
}

// ---------------- Kernel 3: merge segments (bf16 partials) ----------------
__global__ __launch_bounds__(256) void attn_reduce(
    const u16* __restrict__ opart, const float* __restrict__ ml,
    float* __restrict__ out)
{
    const int t   = blockIdx.x;
    const int row = threadIdx.x >> 4;
    const int p   = threadIdx.x & 15;
    const int b   = t & 3;
    const int qt  = 127 - (t >> 2);

    float m[NSEG], l[NSEG];
    #pragma unroll
    for (int s = 0; s < NSEG; ++s) {
        m[s] = ml[(size_t)(t * NSEG + s) * 32 + row * 2];
        l[s] = ml[(size_t)(t * NSEG + s) * 32 + row * 2 + 1];
    }
    float M = m[0];
    #pragma unroll
    for (int s = 1; s < NSEG; ++s) M = fmaxf(M, m[s]);

    float a0 = 0.f, a1 = 0.f, a2 = 0.f, a3 = 0.f, Lsum = 0.f;
    #pragma unroll
    for (int s = 0; s < NSEG; ++s) {
        float wgt = __expf(m[s] - M);
        Lsum += l[s] * wgt;
        uint2 o = *(const uint2*)(opart + (size_t)(t * NSEG + s) * 1024 + row * 64 + p * 4);
        a0 += wgt * bf2f(o.x & 0xffffu);
        a1 += wgt * bf2f(o.x >> 16);
        a2 += wgt * bf2f(o.y & 0xffffu);
        a3 += wgt * bf2f(o.y >> 16);
    }
    float inv = 1.f / Lsum;
    float4 r; r.x = a0 * inv; r.y = a1 * inv; r.z = a2 * inv; r.w = a3 * inv;
    *(float4*)(out + ((size_t)b * T_ + qt * 16 + row) * H_ + p * 4) = r;
}

extern "C" void kernel_launch(void* const* d_in, const int* in_sizes, int n_in,
                              void* d_out, int out_size, void* d_ws, size_t ws_size,
                              hipStream_t stream) {
    const float* x  = (const float*)d_in[0];
    const float* wq = (const float*)d_in[1];
    const float* wk = (const float*)d_in[2];
    const float* wv = (const float*)d_in[3];

    u16* qws  = (u16*)d_ws;                          // 1 MB
    u16* kws  = qws + (size_t)B_ * T_ * H_;          // 1 MB
    u16* vTws = kws + (size_t)B_ * T_ * H_;          // 1 MB
    u16* wcat = vTws + (size_t)B_ * T_ * H_;         // 384 KB
    u16* opart = wcat + (size_t)192 * C_;            // 4096*1024 u16 = 8.4 MB
    float* mlbuf = (float*)(opart + (size_t)4096 * 1024);  // 512 KB

    wcvt<<<192, 256, 0, stream>>>(wq, wk, wv, wcat);
    qkv<<<256, 512, 0, stream>>>(x, wcat, qws, kws, vTws);
    attn_part<<<4096, 64, 0, stream>>>(qws, kws, vTws, opart, mlbuf);
    attn_reduce<<<512, 256, 0, stream>>>(opart, mlbuf, (float*)d_out);
}